// Round 1
// 529.926 us; speedup vs baseline: 1.0207x; 1.0207x over previous
//
#include <hip/hip_runtime.h>
#include <hip/hip_bf16.h>
#include <math.h>

#define BB 32
#define SS 4096
#define EE 512
#define AA 512

typedef short bf16x8 __attribute__((ext_vector_type(8)));
typedef float f32x4 __attribute__((ext_vector_type(4)));
typedef unsigned short u16x4 __attribute__((ext_vector_type(4)));

__device__ __forceinline__ unsigned short f2bf(float f) {
  unsigned int u = __float_as_uint(f);
  u += 0x7fffu + ((u >> 16) & 1u);   // RNE (finite normals)
  return (unsigned short)(u >> 16);
}

__device__ __forceinline__ float bf2f(unsigned short s) {
  return __uint_as_float(((unsigned int)s) << 16);
}

__device__ __forceinline__ float tanh_fast(float x) {
  return 1.f - 2.f / (__expf(2.f * x) + 1.f);
}

// q[b][a] = sum_e h[b][e] * Wh[e][a]
__global__ void query_kernel(const float* __restrict__ h,
                             const float* __restrict__ Wh,
                             float* __restrict__ q) {
  __shared__ float hrow[EE];
  int b = blockIdx.x;
  int t = threadIdx.x;
  for (int i = t; i < EE; i += 256) hrow[i] = h[b * EE + i];
  __syncthreads();
  float a0 = 0.f, a1 = 0.f;
  for (int e = 0; e < EE; ++e) {
    float hv = hrow[e];
    a0 += hv * Wh[e * AA + t];
    a1 += hv * Wh[e * AA + t + 256];
  }
  q[b * AA + t] = a0;
  q[b * AA + t + 256] = a1;
}

// Wst[a][e] = bf16(Ws[e][a])  -- LDS-tiled transpose, coalesced both sides
__global__ void wst_kernel(const float* __restrict__ Ws,
                           unsigned short* __restrict__ Wst) {
  __shared__ unsigned short tile[64][65];
  const int a0 = blockIdx.x * 64, e0 = blockIdx.y * 64;
  const int t = threadIdx.x;
  const int c = t & 63, r0 = t >> 6;
#pragma unroll
  for (int i = 0; i < 16; ++i) {
    int e = r0 + i * 4;                                  // e-within
    tile[c][e] = f2bf(Ws[(size_t)(e0 + e) * AA + a0 + c]);   // read coalesced in a
  }
  __syncthreads();
#pragma unroll
  for (int i = 0; i < 16; ++i) {
    int a = r0 + i * 4;                                  // a-within
    Wst[(size_t)(a0 + a) * EE + e0 + c] = tile[a][c];    // write coalesced in e
  }
}

// Fused: per block (chunk=blockIdx.x -> 64 s-rows, b=blockIdx.y), 512 threads:
//  Pipelined: per 64-col K-chunk {convert+ds_write c | issue loads c+1 |
//  lgkmcnt(0) | raw s_barrier | MFMA chunk c}. Chunk LDS regions are disjoint
//  and written once -> single barrier per chunk, loads stay in flight across it.
__global__ __launch_bounds__(512, 4) void fused_kernel(
    const float* __restrict__ enc, const unsigned short* __restrict__ Wst,
    const float* __restrict__ q, const float* __restrict__ v,
    const int* __restrict__ mask,
    float* __restrict__ rawscore,   // -> attn region of d_out
    float* __restrict__ ctxp,       // [32][64][512]
    float* __restrict__ mbuf) {     // [32][64]
  __shared__ __align__(16) unsigned short Atile[64 * 512];  // 64 KB
  __shared__ float spart[8][64];
  __shared__ float wrow[64];
  const int b = blockIdx.y, chunk = blockIdx.x;
  const int s0 = chunk * 64;
  const int tid = threadIdx.x;
  const int w = tid >> 6, lane = tid & 63;
  const int quad = lane >> 4, l16 = lane & 15;
  const int n0 = w * 64;            // 8 waves x 64 N-cols

  // ---- staging geometry: thread stages rows {rbase, rbase+32}, float4 c4 ----
  const int rbase = tid >> 4;       // 0..31
  const int c4 = tid & 15;          // float4 within 64-col chunk
  const int sw3 = (rbase & 7) << 3; // swizzle (same for rbase+32)
  const float4* src4 = (const float4*)(enc + ((size_t)b * SS + s0) * EE);
  const float4* g0 = src4 + rbase * 128 + c4;
  const float4* g1 = g0 + 32 * 128;
  unsigned short* st0 = &Atile[rbase * 512 + ((c4 * 4) ^ sw3)];
  unsigned short* st1 = st0 + 32 * 512;

  const unsigned short* wb = Wst + (size_t)(n0 + l16) * EE + quad * 8;

  f32x4 acc[4][4];
#pragma unroll
  for (int m = 0; m < 4; ++m)
#pragma unroll
    for (int j = 0; j < 4; ++j) acc[m][j] = (f32x4){0.f, 0.f, 0.f, 0.f};

  float4 rb[2][2];
  rb[0][0] = g0[0];                 // prologue: chunk 0 loads
  rb[0][1] = g1[0];

#pragma unroll
  for (int c = 0; c < 8; ++c) {
    const int cur = c & 1, nxt = cur ^ 1;
    // convert + write chunk c (compiler waits vmcnt on rb[cur] here)
    {
      float4 x = rb[cur][0];
      u16x4 p;
      p.x = f2bf(x.x); p.y = f2bf(x.y); p.z = f2bf(x.z); p.w = f2bf(x.w);
      *(u16x4*)(st0 + c * 64) = p;
      float4 y = rb[cur][1];
      u16x4 p2;
      p2.x = f2bf(y.x); p2.y = f2bf(y.y); p2.z = f2bf(y.z); p2.w = f2bf(y.w);
      *(u16x4*)(st1 + c * 64) = p2;
    }
    // issue next-chunk loads; they stay in flight across the raw barrier
    if (c < 7) {
      rb[nxt][0] = g0[(c + 1) * 16];
      rb[nxt][1] = g1[(c + 1) * 16];
    }
    asm volatile("s_waitcnt lgkmcnt(0)" ::: "memory");  // ds_writes visible
    __builtin_amdgcn_s_barrier();                        // no vmcnt drain
    // ---- MFMA over k in [c*64, c*64+64) ----
#pragma unroll
    for (int kk = 0; kk < 2; ++kk) {
      const int k0 = c * 64 + kk * 32;
      bf16x8 aF[4];
#pragma unroll
      for (int m = 0; m < 4; ++m) {
        const int row = m * 16 + l16;
        aF[m] = *(const bf16x8*)&Atile[row * 512 +
                                       ((k0 + quad * 8) ^ ((row & 7) << 3))];
      }
#pragma unroll
      for (int j = 0; j < 4; ++j) {
        bf16x8 bF = *(const bf16x8*)&wb[(size_t)j * 16 * EE + k0];
#pragma unroll
        for (int m = 0; m < 4; ++m)
          acc[m][j] = __builtin_amdgcn_mfma_f32_16x16x32_bf16(aF[m], bF,
                                                              acc[m][j], 0, 0, 0);
      }
    }
  }

  // ---- epilogue: tanh + v-weighted accumulate ----
  float srow[4][4];
#pragma unroll
  for (int m = 0; m < 4; ++m)
#pragma unroll
    for (int r = 0; r < 4; ++r) srow[m][r] = 0.f;
#pragma unroll
  for (int j = 0; j < 4; ++j) {
    float qn = q[b * AA + n0 + j * 16 + l16];
    float vn = v[n0 + j * 16 + l16];
#pragma unroll
    for (int m = 0; m < 4; ++m)
#pragma unroll
      for (int r = 0; r < 4; ++r)
        srow[m][r] += tanh_fast(qn + acc[m][j][r]) * vn;
  }
#pragma unroll
  for (int m = 0; m < 4; ++m)
#pragma unroll
    for (int r = 0; r < 4; ++r) {
      float s = srow[m][r];
      s += __shfl_xor(s, 1, 64);
      s += __shfl_xor(s, 2, 64);
      s += __shfl_xor(s, 4, 64);
      s += __shfl_xor(s, 8, 64);
      if (l16 == 0) spart[w][m * 16 + quad * 4 + r] = s;
    }
  __syncthreads();

  // ---- Phase C: masked scores, chunk max, exp weights ----
  if (tid < 64) {
    float raw = 0.f;
#pragma unroll
    for (int ww = 0; ww < 8; ++ww) raw += spart[ww][tid];
    float sc = mask[(size_t)b * SS + s0 + tid] ? -1e9f : raw;
    rawscore[(size_t)b * SS + s0 + tid] = sc;
    float mx = sc;
    for (int off = 1; off < 64; off <<= 1)
      mx = fmaxf(mx, __shfl_xor(mx, off, 64));
    wrow[tid] = __expf(sc - mx);
    if (tid == 0) mbuf[b * 64 + chunk] = mx;
  }
  __syncthreads();

  // ---- Phase D: ctx partial, one e-column per thread ----
  {
    const int e = tid;
    float a = 0.f;
#pragma unroll 8
    for (int row = 0; row < 64; ++row)
      a += wrow[row] * bf2f(Atile[row * 512 + (e ^ ((row & 7) << 3))]);
    ctxp[((size_t)b * 64 + chunk) * EE + e] = a;
  }
}

// Per b: global softmax over raw scores -> attn; combine ctx partials.
__global__ __launch_bounds__(512) void finalize_kernel(
    float* __restrict__ attn, const float* __restrict__ ctxp,
    const float* __restrict__ mbuf, float* __restrict__ ctx) {
  __shared__ float red[16];
  __shared__ float fc[64];
  int b = blockIdx.x, t = threadIdx.x;
  float* row = attn + (size_t)b * SS;
  float vals[8];
  float m = -3e38f;
#pragma unroll
  for (int i = 0; i < 8; ++i) {
    float x = row[i * 512 + t];
    vals[i] = x;
    m = fmaxf(m, x);
  }
  for (int off = 1; off < 64; off <<= 1) m = fmaxf(m, __shfl_xor(m, off, 64));
  int wv = t >> 6, ln = t & 63;
  if (ln == 0) red[wv] = m;
  __syncthreads();
  m = red[0];
#pragma unroll
  for (int i = 1; i < 8; ++i) m = fmaxf(m, red[i]);
  float sum = 0.f;
#pragma unroll
  for (int i = 0; i < 8; ++i) { vals[i] = __expf(vals[i] - m); sum += vals[i]; }
  for (int off = 1; off < 64; off <<= 1) sum += __shfl_xor(sum, off, 64);
  if (ln == 0) red[8 + wv] = sum;
  __syncthreads();
  sum = 0.f;
#pragma unroll
  for (int i = 0; i < 8; ++i) sum += red[8 + i];
  float inv = 1.f / sum;
#pragma unroll
  for (int i = 0; i < 8; ++i) row[i * 512 + t] = vals[i] * inv;

  if (t < 64) fc[t] = __expf(mbuf[b * 64 + t] - m) * inv;
  __syncthreads();
  {
    const float* p = ctxp + (size_t)b * 64 * EE + t;
    float s = 0.f;
#pragma unroll
    for (int c = 0; c < 64; ++c) s += fc[c] * p[c * EE];
    ctx[b * EE + t] = s;
  }
}

extern "C" void kernel_launch(void* const* d_in, const int* in_sizes, int n_in,
                              void* d_out, int out_size, void* d_ws, size_t ws_size,
                              hipStream_t stream) {
  const float* h    = (const float*)d_in[0];
  const float* enc  = (const float*)d_in[1];
  const int*   mask = (const int*)d_in[2];
  const float* Wh   = (const float*)d_in[3];
  const float* Ws   = (const float*)d_in[4];
  const float* v    = (const float*)d_in[5];

  float* out  = (float*)d_out;
  float* ctx  = out;              // [32,512]
  float* attn = out + BB * EE;    // [32,4096]

  char* ws = (char*)d_ws;
  float* qws = (float*)ws;                         ws += (size_t)BB * AA * 4;        // 64 KB
  unsigned short* Wst = (unsigned short*)ws;       ws += (size_t)AA * EE * 2;        // 512 KB
  float* ctxp = (float*)ws;                        ws += (size_t)BB * 64 * EE * 4;   // 4 MB
  float* mbuf = (float*)ws;                                                          // 8 KB

  hipLaunchKernelGGL(query_kernel, dim3(32), dim3(256), 0, stream, h, Wh, qws);
  hipLaunchKernelGGL(wst_kernel, dim3(8, 8), dim3(256), 0, stream, Ws, Wst);
  hipLaunchKernelGGL(fused_kernel, dim3(SS / 64, BB), dim3(512), 0, stream,
                     enc, Wst, qws, v, mask, attn, ctxp, mbuf);
  hipLaunchKernelGGL(finalize_kernel, dim3(BB), dim3(512), 0, stream,
                     attn, ctxp, mbuf, ctx);
}

// Round 2
// 526.481 us; speedup vs baseline: 1.0274x; 1.0065x over previous
//
#include <hip/hip_runtime.h>
#include <hip/hip_bf16.h>
#include <math.h>

#define BB 32
#define SS 4096
#define EE 512
#define AA 512

typedef short bf16x8 __attribute__((ext_vector_type(8)));
typedef float f32x4 __attribute__((ext_vector_type(4)));
typedef unsigned short u16x4 __attribute__((ext_vector_type(4)));

__device__ __forceinline__ unsigned short f2bf(float f) {
  unsigned int u = __float_as_uint(f);
  u += 0x7fffu + ((u >> 16) & 1u);   // RNE (finite normals)
  return (unsigned short)(u >> 16);
}

__device__ __forceinline__ float bf2f(unsigned short s) {
  return __uint_as_float(((unsigned int)s) << 16);
}

__device__ __forceinline__ float tanh_fast(float x) {
  return 1.f - 2.f / (__expf(2.f * x) + 1.f);
}

// q[b][a] = sum_e h[b][e] * Wh[e][a]
__global__ void query_kernel(const float* __restrict__ h,
                             const float* __restrict__ Wh,
                             float* __restrict__ q) {
  __shared__ float hrow[EE];
  int b = blockIdx.x;
  int t = threadIdx.x;
  for (int i = t; i < EE; i += 256) hrow[i] = h[b * EE + i];
  __syncthreads();
  float a0 = 0.f, a1 = 0.f;
  for (int e = 0; e < EE; ++e) {
    float hv = hrow[e];
    a0 += hv * Wh[e * AA + t];
    a1 += hv * Wh[e * AA + t + 256];
  }
  q[b * AA + t] = a0;
  q[b * AA + t + 256] = a1;
}

// Wst[a][e] = bf16(Ws[e][a])  -- LDS-tiled transpose, coalesced both sides
__global__ void wst_kernel(const float* __restrict__ Ws,
                           unsigned short* __restrict__ Wst) {
  __shared__ unsigned short tile[64][65];
  const int a0 = blockIdx.x * 64, e0 = blockIdx.y * 64;
  const int t = threadIdx.x;
  const int c = t & 63, r0 = t >> 6;
#pragma unroll
  for (int i = 0; i < 16; ++i) {
    int e = r0 + i * 4;                                  // e-within
    tile[c][e] = f2bf(Ws[(size_t)(e0 + e) * AA + a0 + c]);   // read coalesced in a
  }
  __syncthreads();
#pragma unroll
  for (int i = 0; i < 16; ++i) {
    int a = r0 + i * 4;                                  // a-within
    Wst[(size_t)(a0 + a) * EE + e0 + c] = tile[a][c];    // write coalesced in e
  }
}

// Fused: per block (chunk=blockIdx.x -> 64 s-rows, b=blockIdx.y), 512 threads.
// 1 block/CU, ~200 arch regs: EVERYTHING prefetched off the critical path.
//  - enc staging: depth-3 register pipeline (rb[3][2]) -> HBM latency hidden
//  - B-panel fragments: double-buffered in registers (bB[2][8]) -> L2 latency hidden
//  - per chunk: convert+ds_write | issue enc c+3 | issue bF c+1 | lgkmcnt(0) |
//    raw s_barrier (no vmcnt drain) | MFMA from regs+LDS only
__global__ __launch_bounds__(512, 2) void fused_kernel(
    const float* __restrict__ enc, const unsigned short* __restrict__ Wst,
    const float* __restrict__ q, const float* __restrict__ v,
    const int* __restrict__ mask,
    float* __restrict__ rawscore,   // -> attn region of d_out
    float* __restrict__ ctxp,       // [32][64][512]
    float* __restrict__ mbuf) {     // [32][64]
  __shared__ __align__(16) unsigned short Atile[64 * 512];  // 64 KB
  __shared__ float spart[8][64];
  __shared__ float wrow[64];
  const int b = blockIdx.y, chunk = blockIdx.x;
  const int s0 = chunk * 64;
  const int tid = threadIdx.x;
  const int w = tid >> 6, lane = tid & 63;
  const int quad = lane >> 4, l16 = lane & 15;
  const int n0 = w * 64;            // 8 waves x 64 N-cols

  // ---- staging geometry: thread stages rows {rbase, rbase+32}, float4 c4 ----
  const int rbase = tid >> 4;       // 0..31
  const int c4 = tid & 15;          // float4 within 64-col chunk
  const int sw3 = (rbase & 7) << 3; // swizzle (same for rbase+32)
  const float4* src4 = (const float4*)(enc + ((size_t)b * SS + s0) * EE);
  const float4* g0 = src4 + rbase * 128 + c4;
  const float4* g1 = g0 + 32 * 128;
  unsigned short* st0 = &Atile[rbase * 512 + ((c4 * 4) ^ sw3)];
  unsigned short* st1 = st0 + 32 * 512;

  const unsigned short* wb = Wst + (size_t)(n0 + l16) * EE + quad * 8;

  f32x4 acc[4][4];
#pragma unroll
  for (int m = 0; m < 4; ++m)
#pragma unroll
    for (int j = 0; j < 4; ++j) acc[m][j] = (f32x4){0.f, 0.f, 0.f, 0.f};

  // ---- prologue: enc chunks 0..2 in flight, bF chunk 0 in flight ----
  float4 rb[3][2];
  rb[0][0] = g0[0];   rb[0][1] = g1[0];
  rb[1][0] = g0[16];  rb[1][1] = g1[16];
  rb[2][0] = g0[32];  rb[2][1] = g1[32];

  bf16x8 bB[2][8];
#pragma unroll
  for (int kk = 0; kk < 2; ++kk)
#pragma unroll
    for (int j = 0; j < 4; ++j)
      bB[0][kk * 4 + j] = *(const bf16x8*)&wb[(size_t)j * 16 * EE + kk * 32];

#pragma unroll
  for (int c = 0; c < 8; ++c) {
    const int cs = c % 3, cur = c & 1, nxt = cur ^ 1;
    // convert + write chunk c (vmcnt wait lands here, loads issued 3 chunks ago)
    {
      float4 x = rb[cs][0];
      u16x4 p;
      p.x = f2bf(x.x); p.y = f2bf(x.y); p.z = f2bf(x.z); p.w = f2bf(x.w);
      *(u16x4*)(st0 + c * 64) = p;
      float4 y = rb[cs][1];
      u16x4 p2;
      p2.x = f2bf(y.x); p2.y = f2bf(y.y); p2.z = f2bf(y.z); p2.w = f2bf(y.w);
      *(u16x4*)(st1 + c * 64) = p2;
    }
    // issue enc loads 3 chunks ahead
    if (c + 3 < 8) {
      rb[(c + 3) % 3][0] = g0[(c + 3) * 16];
      rb[(c + 3) % 3][1] = g1[(c + 3) * 16];
    }
    // issue next chunk's B fragments (L2) -> land during this chunk's MFMA
    if (c + 1 < 8) {
#pragma unroll
      for (int kk = 0; kk < 2; ++kk)
#pragma unroll
        for (int j = 0; j < 4; ++j)
          bB[nxt][kk * 4 + j] =
              *(const bf16x8*)&wb[(size_t)j * 16 * EE + (c + 1) * 64 + kk * 32];
    }
    asm volatile("s_waitcnt lgkmcnt(0)" ::: "memory");  // my ds_writes committed
    __builtin_amdgcn_s_barrier();                        // no vmcnt drain
    // ---- MFMA over k in [c*64, c*64+64): operands from LDS + registers ----
#pragma unroll
    for (int kk = 0; kk < 2; ++kk) {
      const int k0 = c * 64 + kk * 32;
      bf16x8 aF[4];
#pragma unroll
      for (int m = 0; m < 4; ++m) {
        const int row = m * 16 + l16;
        aF[m] = *(const bf16x8*)&Atile[row * 512 +
                                       ((k0 + quad * 8) ^ ((row & 7) << 3))];
      }
#pragma unroll
      for (int j = 0; j < 4; ++j) {
#pragma unroll
        for (int m = 0; m < 4; ++m)
          acc[m][j] = __builtin_amdgcn_mfma_f32_16x16x32_bf16(
              aF[m], bB[cur][kk * 4 + j], acc[m][j], 0, 0, 0);
      }
    }
  }

  // ---- epilogue: tanh + v-weighted accumulate ----
  float srow[4][4];
#pragma unroll
  for (int m = 0; m < 4; ++m)
#pragma unroll
    for (int r = 0; r < 4; ++r) srow[m][r] = 0.f;
#pragma unroll
  for (int j = 0; j < 4; ++j) {
    float qn = q[b * AA + n0 + j * 16 + l16];
    float vn = v[n0 + j * 16 + l16];
#pragma unroll
    for (int m = 0; m < 4; ++m)
#pragma unroll
      for (int r = 0; r < 4; ++r)
        srow[m][r] += tanh_fast(qn + acc[m][j][r]) * vn;
  }
#pragma unroll
  for (int m = 0; m < 4; ++m)
#pragma unroll
    for (int r = 0; r < 4; ++r) {
      float s = srow[m][r];
      s += __shfl_xor(s, 1, 64);
      s += __shfl_xor(s, 2, 64);
      s += __shfl_xor(s, 4, 64);
      s += __shfl_xor(s, 8, 64);
      if (l16 == 0) spart[w][m * 16 + quad * 4 + r] = s;
    }
  __syncthreads();

  // ---- Phase C: masked scores, chunk max, exp weights ----
  if (tid < 64) {
    float raw = 0.f;
#pragma unroll
    for (int ww = 0; ww < 8; ++ww) raw += spart[ww][tid];
    float sc = mask[(size_t)b * SS + s0 + tid] ? -1e9f : raw;
    rawscore[(size_t)b * SS + s0 + tid] = sc;
    float mx = sc;
    for (int off = 1; off < 64; off <<= 1)
      mx = fmaxf(mx, __shfl_xor(mx, off, 64));
    wrow[tid] = __expf(sc - mx);
    if (tid == 0) mbuf[b * 64 + chunk] = mx;
  }
  __syncthreads();

  // ---- Phase D: ctx partial, one e-column per thread ----
  {
    const int e = tid;
    float a = 0.f;
#pragma unroll 8
    for (int row = 0; row < 64; ++row)
      a += wrow[row] * bf2f(Atile[row * 512 + (e ^ ((row & 7) << 3))]);
    ctxp[((size_t)b * 64 + chunk) * EE + e] = a;
  }
}

// Per b: global softmax over raw scores -> attn; combine ctx partials.
__global__ __launch_bounds__(512) void finalize_kernel(
    float* __restrict__ attn, const float* __restrict__ ctxp,
    const float* __restrict__ mbuf, float* __restrict__ ctx) {
  __shared__ float red[16];
  __shared__ float fc[64];
  int b = blockIdx.x, t = threadIdx.x;
  float* row = attn + (size_t)b * SS;
  float vals[8];
  float m = -3e38f;
#pragma unroll
  for (int i = 0; i < 8; ++i) {
    float x = row[i * 512 + t];
    vals[i] = x;
    m = fmaxf(m, x);
  }
  for (int off = 1; off < 64; off <<= 1) m = fmaxf(m, __shfl_xor(m, off, 64));
  int wv = t >> 6, ln = t & 63;
  if (ln == 0) red[wv] = m;
  __syncthreads();
  m = red[0];
#pragma unroll
  for (int i = 1; i < 8; ++i) m = fmaxf(m, red[i]);
  float sum = 0.f;
#pragma unroll
  for (int i = 0; i < 8; ++i) { vals[i] = __expf(vals[i] - m); sum += vals[i]; }
  for (int off = 1; off < 64; off <<= 1) sum += __shfl_xor(sum, off, 64);
  if (ln == 0) red[8 + wv] = sum;
  __syncthreads();
  sum = 0.f;
#pragma unroll
  for (int i = 0; i < 8; ++i) sum += red[8 + i];
  float inv = 1.f / sum;
#pragma unroll
  for (int i = 0; i < 8; ++i) row[i * 512 + t] = vals[i] * inv;

  if (t < 64) fc[t] = __expf(mbuf[b * 64 + t] - m) * inv;
  __syncthreads();
  {
    const float* p = ctxp + (size_t)b * 64 * EE + t;
    float s = 0.f;
#pragma unroll
    for (int c = 0; c < 64; ++c) s += fc[c] * p[c * EE];
    ctx[b * EE + t] = s;
  }
}

extern "C" void kernel_launch(void* const* d_in, const int* in_sizes, int n_in,
                              void* d_out, int out_size, void* d_ws, size_t ws_size,
                              hipStream_t stream) {
  const float* h    = (const float*)d_in[0];
  const float* enc  = (const float*)d_in[1];
  const int*   mask = (const int*)d_in[2];
  const float* Wh   = (const float*)d_in[3];
  const float* Ws   = (const float*)d_in[4];
  const float* v    = (const float*)d_in[5];

  float* out  = (float*)d_out;
  float* ctx  = out;              // [32,512]
  float* attn = out + BB * EE;    // [32,4096]

  char* ws = (char*)d_ws;
  float* qws = (float*)ws;                         ws += (size_t)BB * AA * 4;        // 64 KB
  unsigned short* Wst = (unsigned short*)ws;       ws += (size_t)AA * EE * 2;        // 512 KB
  float* ctxp = (float*)ws;                        ws += (size_t)BB * 64 * EE * 4;   // 4 MB
  float* mbuf = (float*)ws;                                                          // 8 KB

  hipLaunchKernelGGL(query_kernel, dim3(32), dim3(256), 0, stream, h, Wh, qws);
  hipLaunchKernelGGL(wst_kernel, dim3(8, 8), dim3(256), 0, stream, Ws, Wst);
  hipLaunchKernelGGL(fused_kernel, dim3(SS / 64, BB), dim3(512), 0, stream,
                     enc, Wst, qws, v, mask, attn, ctxp, mbuf);
  hipLaunchKernelGGL(finalize_kernel, dim3(BB), dim3(512), 0, stream,
                     attn, ctxp, mbuf, ctx);
}